// Round 9
// baseline (292.013 us; speedup 1.0000x reference)
//
#include <hip/hip_runtime.h>
#include <hip/hip_bf16.h>

#define B_ 4096
#define D_ 1024
#define H_ 8192
#define O_ 1000
#define K2 2048          // physical packed K ([hi|lo])
#define NT 48            // logical K-tiles: 3072 / 64

typedef __attribute__((ext_vector_type(8))) short short8;
typedef __attribute__((ext_vector_type(4))) short short4v;
typedef __attribute__((ext_vector_type(16))) float f32x16;

union BF4 { __hip_bfloat16 b[4]; short4v s; };

__device__ __forceinline__ void gload16(void* ldsp, const void* g) {
  __builtin_amdgcn_global_load_lds(
      (const __attribute__((address_space(1))) unsigned int*)g,
      (__attribute__((address_space(3))) unsigned int*)ldsp, 16, 0, 0);
}

// K-tile T -> column offset in packed [hi|lo] rows. bf16x3 interleave:
// T = 3t+r: r0 = xh*wh, r1 = xl*wh, r2 = xh*wl.
__device__ __forceinline__ int aoff_(int T) {
  const int t = T / 3, r = T - 3 * t;
  return (r == 1 ? 1024 : 0) + t * 64;
}
__device__ __forceinline__ int boff_(int T) {
  const int t = T / 3, r = T - 3 * t;
  return (r == 2 ? 1024 : 0) + t * 64;
}

// ---- merged split: fp32 -> [hi|lo] bf16 + sum-of-squares + keys init ----
__global__ __launch_bounds__(256) void split_all_kernel(
    const float* __restrict__ x, const float* __restrict__ w,
    __hip_bfloat16* __restrict__ Ap, __hip_bfloat16* __restrict__ Bp,
    float* __restrict__ xsq, float* __restrict__ wsq,
    unsigned long long* __restrict__ keys)
{
  const int r = blockIdx.x;
  const int t = threadIdx.x;
  const float* src;
  __hip_bfloat16* dst;
  float* sq;
  if (r < B_) {
    src = x + (size_t)r * D_; dst = Ap + (size_t)r * K2; sq = xsq + r;
    if (t == 0) keys[r] = ~0ULL;
  } else {
    const int rr = r - B_;
    src = w + (size_t)rr * D_; dst = Bp + (size_t)rr * K2; sq = wsq + rr;
  }
  const float4 v = ((const float4*)src)[t];
  float ss = v.x * v.x + v.y * v.y + v.z * v.z + v.w * v.w;

  BF4 Hh, Ll;
  const float e[4] = {v.x, v.y, v.z, v.w};
#pragma unroll
  for (int i = 0; i < 4; ++i) {
    __hip_bfloat16 h = __float2bfloat16(e[i]);
    Hh.b[i] = h;
    Ll.b[i] = __float2bfloat16(e[i] - __bfloat162float(h));
  }
  *(short4v*)(dst + t * 4) = Hh.s;
  *(short4v*)(dst + 1024 + t * 4) = Ll.s;

#pragma unroll
  for (int o = 32; o > 0; o >>= 1) ss += __shfl_down(ss, o);
  __shared__ float wsum[4];
  if ((t & 63) == 0) wsum[t >> 6] = ss;
  __syncthreads();
  if (t == 0) *sq = (wsum[0] + wsum[1]) + (wsum[2] + wsum[3]);
}

// ---- 256x256 GEMM via mfma_32x32x16, geometric-min LDS reads ----
// LDS dbuf d: A0@d+0 (rows 0-127, waves wm=0), A1@d+16K (128-255, wm=1),
// B0@d+32K (cols 0-127, wn=0,1), B1@d+48K (cols 128-255, wn=2,3).
// 128B rows (64 k); phys 16B-unit = logical ^ (row&7) via pre-swizzled src.
// Per tile (K=64): 4 kk-phases; per phase per wave 6 ds_read_b128
// (4 A m-blocks + 2 B n-blocks) + 8 mfma_32x32x16. Reads issued 1 phase
// ahead (asm, lgkmcnt(6) counted), f0/f1 register ping-pong (static).
// Stages: tile T+1's 4 halves during T phases 0-1 (lead >= 2.5 phases);
// gate vmcnt(0) + single barrier at tile entry.
// WAR: T+1 stages write dbuf^1 whose readers (tile T-1) all drained
// before the tile-T entry barrier.

#define BAR() do { asm volatile("" ::: "memory"); \
                   __builtin_amdgcn_s_barrier(); \
                   asm volatile("" ::: "memory"); } while (0)
#define SB0() __builtin_amdgcn_sched_barrier(0)
#define GATEV0() asm volatile("s_waitcnt vmcnt(0)")
#define LGKM6() do { asm volatile("s_waitcnt lgkmcnt(6)"); SB0(); } while (0)
#define LGKM0() do { asm volatile("s_waitcnt lgkmcnt(0)"); SB0(); } while (0)

#define DSR(dst, base, OFF) \
  asm volatile("ds_read_b128 %0, %1 offset:" OFF : "=v"(dst) : "v"(base))

// 6 reads for kk-granule KK (literal): 4 A (m*32 rows) + 2 B (n*32 cols)
#define RDP(F, DSEL, KK) do { \
    const unsigned a_ = aB + (DSEL) + ofk##KK; \
    const unsigned b_ = bB + (DSEL) + ofk##KK; \
    DSR(F[0], a_, "0");    DSR(F[1], a_, "4096"); \
    DSR(F[2], a_, "8192"); DSR(F[3], a_, "12288"); \
    DSR(F[4], b_, "0");    DSR(F[5], b_, "4096"); \
  } while (0)

#define STAGE(P, prow, T, isB, h) do { if ((T) < NT) { \
    const int koff_ = (isB) ? boff_(T) : aoff_(T); \
    const __hip_bfloat16* s_ = (P) + (size_t)((prow) + (h)*128 + wid*16 + srow) * K2 + koff_ + sunit * 8; \
    char* d_ = lds + ((T)&1)*65536 + (isB)*32768 + (h)*16384 + wid*2048 + lane*16; \
    gload16(d_, s_); gload16(d_ + 1024, s_ + 8*K2); } } while (0)

#define MFMA32(a, b, c) __builtin_amdgcn_mfma_f32_32x32x16_bf16(a, b, c, 0, 0, 0)

#define MMQ32(F) do { \
    __builtin_amdgcn_s_setprio(1); \
    acc[0][0] = MFMA32(F[0], F[4], acc[0][0]); \
    acc[0][1] = MFMA32(F[0], F[5], acc[0][1]); \
    acc[1][0] = MFMA32(F[1], F[4], acc[1][0]); \
    acc[1][1] = MFMA32(F[1], F[5], acc[1][1]); \
    acc[2][0] = MFMA32(F[2], F[4], acc[2][0]); \
    acc[2][1] = MFMA32(F[2], F[5], acc[2][1]); \
    acc[3][0] = MFMA32(F[3], F[4], acc[3][0]); \
    acc[3][1] = MFMA32(F[3], F[5], acc[3][1]); \
    __builtin_amdgcn_s_setprio(0); \
    SB0(); } while (0)

// One K-tile (4 phases). DSEL compile-time (0 / 65536).
#define TILE32(DSEL, T) do { \
    GATEV0(); BAR(); \
    RDP(f0, DSEL, 0); \
    RDP(f1, DSEL, 1); \
    STAGE(Ap, brow, (T) + 1, 0, 0); \
    STAGE(Bp, bcol, (T) + 1, 1, 0); \
    LGKM6(); MMQ32(f0); \
    RDP(f0, DSEL, 2); \
    STAGE(Ap, brow, (T) + 1, 0, 1); \
    STAGE(Bp, bcol, (T) + 1, 1, 1); \
    LGKM6(); MMQ32(f1); \
    RDP(f1, DSEL, 3); \
    LGKM6(); MMQ32(f0); \
    LGKM0(); MMQ32(f1); \
  } while (0)

__global__ __launch_bounds__(512, 2) void gemm_argmin_kernel(
    const __hip_bfloat16* __restrict__ Ap, const __hip_bfloat16* __restrict__ Bp,
    const float* __restrict__ xsq, const float* __restrict__ wsq,
    unsigned long long* __restrict__ keys)
{
  __shared__ char lds[131072];

  const int t = threadIdx.x;
  // XCD-aware: square 8x8 tile-chunk per XCD (r4-proven).
  const int id = blockIdx.x;
  const int xcd = id & 7;
  const int r_ = id >> 3;
  const int by = (xcd >> 2) * 8 + (r_ >> 3);
  const int bx = (xcd & 3) * 8 + (r_ & 7);
  const int brow = by * 256, bcol = bx * 256;

  const int lane = t & 63, wid = t >> 6;
  const int wm = wid >> 2, wn = wid & 3;   // wave tile 128 rows x 64 cols
  const int c31 = lane & 31;               // frag row/col
  const int kh = lane >> 5;                // k-half within 16-k granule
  const int swz = lane & 7;

  // per-lane swizzled 16B-unit offsets for kk=0..3 (unit = kk*2+kh, ^ row&7)
  const unsigned ofk0 = (unsigned)(((0 + kh) ^ swz) * 16);
  const unsigned ofk1 = (unsigned)(((2 + kh) ^ swz) * 16);
  const unsigned ofk2 = (unsigned)(((4 + kh) ^ swz) * 16);
  const unsigned ofk3 = (unsigned)(((6 + kh) ^ swz) * 16);

  const unsigned lb = (unsigned)(uintptr_t)lds;
  const unsigned aB = lb + (unsigned)(wm * 16384 + c31 * 128);
  const unsigned bB = lb + (unsigned)(32768 + (wn >> 1) * 16384 +
                                      ((wn & 1) * 64 + c31) * 128);

  const int srow = lane >> 3;
  const int sunit = (lane & 7) ^ srow;

  f32x16 acc[4][2] = {};
  short8 f0[6], f1[6];

  // Prologue: stage tile0's 4 halves (8 gload instrs; drained at tile0 gate)
  STAGE(Ap, brow, 0, 0, 0);
  STAGE(Ap, brow, 0, 0, 1);
  STAGE(Bp, bcol, 0, 1, 0);
  STAGE(Bp, bcol, 0, 1, 1);

  for (int tt = 0; tt < NT; tt += 2) {
    TILE32(0, tt);
    TILE32(65536, tt + 1);
  }

  // Epilogue: s = (x_sq - 2*dot) + w_sq (reference fp32 rounding order).
  // 32x32 C/D (m74/m101, r2-validated): col = lane&31,
  // row = (reg&3) + 8*(reg>>2) + 4*(lane>>5).
#pragma unroll
  for (int m = 0; m < 4; ++m) {
#pragma unroll
    for (int rg = 0; rg < 16; ++rg) {
      const int row = brow + wm * 128 + m * 32 + (rg & 3) + 8 * (rg >> 2) + 4 * kh;
      const float xs = xsq[row];
      unsigned long long best = ~0ULL;
#pragma unroll
      for (int n = 0; n < 2; ++n) {
        const int col = bcol + wn * 64 + n * 32 + c31;
        const float s = (xs - 2.0f * acc[m][n][rg]) + wsq[col];
        unsigned ub = __float_as_uint(s);
        ub = (ub & 0x80000000u) ? ~ub : (ub | 0x80000000u);
        const unsigned long long key =
            ((unsigned long long)ub << 32) | (unsigned)col;
        if (key < best) best = key;
      }
#pragma unroll
      for (int o = 1; o < 32; o <<= 1) {   // reduce within each 32-lane half
        const unsigned long long v = __shfl_xor(best, o);
        if (v < best) best = v;
      }
      if (c31 == 0) atomicMin(&keys[row], best);
    }
  }
}

// ---- transpose G [O,H] -> GT [H,O] ----
__global__ __launch_bounds__(256) void transposeG_kernel(
    const float* __restrict__ G, float* __restrict__ GT)
{
  __shared__ float tile[32][33];
  const int h0 = blockIdx.x * 32;
  const int o0 = blockIdx.y * 32;
  const int tx = threadIdx.x;
  const int ty = threadIdx.y;
#pragma unroll
  for (int j = 0; j < 4; ++j) {
    const int o = o0 + ty + j * 8;
    if (o < O_) tile[ty + j * 8][tx] = G[(size_t)o * H_ + h0 + tx];
  }
  __syncthreads();
  const int o = o0 + tx;
  if (o < O_) {
#pragma unroll
    for (int j = 0; j < 4; ++j)
      GT[(size_t)(h0 + ty + j * 8) * O_ + o] = tile[tx][ty + j * 8];
  }
}

// ---- winners + row gather ----
__global__ __launch_bounds__(256) void finalize_kernel(
    const unsigned long long* __restrict__ keys,
    const float* __restrict__ GT, float* __restrict__ out)
{
  const int b = blockIdx.x;
  const unsigned w = (unsigned)(keys[b] & 0xFFFFFFFFull);
  if (threadIdx.x == 0) out[(size_t)B_ * O_ + b] = (float)w;
  const float4* src = (const float4*)(GT + (size_t)w * O_);
  float4* dst = (float4*)(out + (size_t)b * O_);
  for (int i = threadIdx.x; i < O_ / 4; i += 256) dst[i] = src[i];
}

extern "C" void kernel_launch(void* const* d_in, const int* in_sizes, int n_in,
                              void* d_out, int out_size, void* d_ws, size_t ws_size,
                              hipStream_t stream)
{
  (void)in_sizes; (void)n_in; (void)out_size; (void)ws_size;
  const float* x = (const float*)d_in[0];
  const float* kw = (const float*)d_in[1];
  const float* gw = (const float*)d_in[2];
  float* out = (float*)d_out;

  char* ws = (char*)d_ws;
  // A' 16.78MB | B' 33.55MB | xsq 16KB | wsq 32KB | keys 32KB ; GT overlays A'/B'
  __hip_bfloat16* Ap = (__hip_bfloat16*)(ws);
  __hip_bfloat16* Bp = (__hip_bfloat16*)(ws + 16777216);
  float* xsq = (float*)(ws + 50331648);
  float* wsq = (float*)(ws + 50331648 + 16384);
  unsigned long long* keys = (unsigned long long*)(ws + 50331648 + 16384 + 32768);
  float* GT = (float*)(ws);  // dead A'/B' space after GEMM

  split_all_kernel<<<B_ + H_, 256, 0, stream>>>(x, kw, Ap, Bp, xsq, wsq, keys);
  gemm_argmin_kernel<<<512, 512, 0, stream>>>(Ap, Bp, xsq, wsq, keys);
  transposeG_kernel<<<dim3(H_ / 32, (O_ + 31) / 32), dim3(32, 8), 0, stream>>>(gw, GT);
  finalize_kernel<<<B_, 256, 0, stream>>>(keys, GT, out);
}

// Round 10
// 288.594 us; speedup vs baseline: 1.0118x; 1.0118x over previous
//
#include <hip/hip_runtime.h>
#include <hip/hip_bf16.h>

#define B_ 4096
#define D_ 1024
#define H_ 8192
#define O_ 1000
#define K2 2048          // physical packed K ([hi|lo])
#define NT 48            // logical K-tiles: 3072 / 64

typedef __attribute__((ext_vector_type(8))) short short8;
typedef __attribute__((ext_vector_type(4))) short short4v;
typedef __attribute__((ext_vector_type(16))) float f32x16;

union BF4 { __hip_bfloat16 b[4]; short4v s; };

__device__ __forceinline__ void gload16(void* ldsp, const void* g) {
  __builtin_amdgcn_global_load_lds(
      (const __attribute__((address_space(1))) unsigned int*)g,
      (__attribute__((address_space(3))) unsigned int*)ldsp, 16, 0, 0);
}

// K-tile T -> column offset in packed [hi|lo] rows. bf16x3 interleave:
// T = 3t+r: r0 = xh*wh, r1 = xl*wh, r2 = xh*wl.
__device__ __forceinline__ int aoff_(int T) {
  const int t = T / 3, r = T - 3 * t;
  return (r == 1 ? 1024 : 0) + t * 64;
}
__device__ __forceinline__ int boff_(int T) {
  const int t = T / 3, r = T - 3 * t;
  return (r == 2 ? 1024 : 0) + t * 64;
}

// ---- merged split: fp32 -> [hi|lo] bf16 + sum-of-squares + keys init ----
__global__ __launch_bounds__(256) void split_all_kernel(
    const float* __restrict__ x, const float* __restrict__ w,
    __hip_bfloat16* __restrict__ Ap, __hip_bfloat16* __restrict__ Bp,
    float* __restrict__ xsq, float* __restrict__ wsq,
    unsigned long long* __restrict__ keys)
{
  const int r = blockIdx.x;
  const int t = threadIdx.x;
  const float* src;
  __hip_bfloat16* dst;
  float* sq;
  if (r < B_) {
    src = x + (size_t)r * D_; dst = Ap + (size_t)r * K2; sq = xsq + r;
    if (t == 0) keys[r] = ~0ULL;
  } else {
    const int rr = r - B_;
    src = w + (size_t)rr * D_; dst = Bp + (size_t)rr * K2; sq = wsq + rr;
  }
  const float4 v = ((const float4*)src)[t];
  float ss = v.x * v.x + v.y * v.y + v.z * v.z + v.w * v.w;

  BF4 Hh, Ll;
  const float e[4] = {v.x, v.y, v.z, v.w};
#pragma unroll
  for (int i = 0; i < 4; ++i) {
    __hip_bfloat16 h = __float2bfloat16(e[i]);
    Hh.b[i] = h;
    Ll.b[i] = __float2bfloat16(e[i] - __bfloat162float(h));
  }
  *(short4v*)(dst + t * 4) = Hh.s;
  *(short4v*)(dst + 1024 + t * 4) = Ll.s;

#pragma unroll
  for (int o = 32; o > 0; o >>= 1) ss += __shfl_down(ss, o);
  __shared__ float wsum[4];
  if ((t & 63) == 0) wsum[t >> 6] = ss;
  __syncthreads();
  if (t == 0) *sq = (wsum[0] + wsum[1]) + (wsum[2] + wsum[3]);
}

// ---- 256x256 GEMM via mfma_32x32x16, geometric-min LDS reads ----
// LDS dbuf d: A0@d+0 (rows 0-127, wm=0), A1@d+16K (wm=1),
// B0@d+32K (cols 0-127, wn=0,1), B1@d+48K (cols 128-255, wn=2,3).
// 128B rows; SWIZZLE: phys 16B-unit = logical ^ f(row),
// f(row) = (row&7) ^ ((row>>3)&3)   [r9 post-mortem: row&7 alone is a
// 4-way conflict in stride-8 lane groups; adding (row>>3)&3 makes both
// consecutive-8 (8 distinct) and stride-8 (2-way, free) groupings clean].
// Per tile (K=64): 4 kk-phases; 6 ds_read_b128 + 8 mfma_32x32x16 per phase,
// reads 1 phase ahead (asm, lgkmcnt(6) counted), f0/f1 ping-pong.
// Stages: tile T+1's 4 halves during T phases 0-1; gate vmcnt(0) + single
// barrier at tile entry. WAR: T+1 stages write dbuf^1 whose readers
// (tile T-1) drained before the tile-T entry barrier.

#define BAR() do { asm volatile("" ::: "memory"); \
                   __builtin_amdgcn_s_barrier(); \
                   asm volatile("" ::: "memory"); } while (0)
#define SB0() __builtin_amdgcn_sched_barrier(0)
#define GATEV0() asm volatile("s_waitcnt vmcnt(0)")
#define LGKM6() do { asm volatile("s_waitcnt lgkmcnt(6)"); SB0(); } while (0)
#define LGKM0() do { asm volatile("s_waitcnt lgkmcnt(0)"); SB0(); } while (0)

#define DSR(dst, base, OFF) \
  asm volatile("ds_read_b128 %0, %1 offset:" OFF : "=v"(dst) : "v"(base))

// 6 reads for kk-granule KK (literal): 4 A (m*32 rows) + 2 B (n*32 cols)
#define RDP(F, DSEL, KK) do { \
    const unsigned a_ = aB + (DSEL) + ofk##KK; \
    const unsigned b_ = bB + (DSEL) + ofk##KK; \
    DSR(F[0], a_, "0");    DSR(F[1], a_, "4096"); \
    DSR(F[2], a_, "8192"); DSR(F[3], a_, "12288"); \
    DSR(F[4], b_, "0");    DSR(F[5], b_, "4096"); \
  } while (0)

// Stage one 128-row half: linear LDS dst, f-swizzled global source.
// First gload covers region rows wid*16+srow (f = srow ^ (2wid&3)),
// second covers wid*16+8+srow (f = srow ^ ((2wid+1)&3)).
#define STAGE(P, prow, T, isB, h) do { if ((T) < NT) { \
    const int koff_ = (isB) ? boff_(T) : aoff_(T); \
    const __hip_bfloat16* s0_ = (P) + (size_t)((prow) + (h)*128 + wid*16 + srow) * K2 + koff_ + sunit0 * 8; \
    const __hip_bfloat16* s1_ = (P) + (size_t)((prow) + (h)*128 + wid*16 + 8 + srow) * K2 + koff_ + sunit1 * 8; \
    char* d_ = lds + ((T)&1)*65536 + (isB)*32768 + (h)*16384 + wid*2048 + lane*16; \
    gload16(d_, s0_); gload16(d_ + 1024, s1_); } } while (0)

#define MFMA32(a, b, c) __builtin_amdgcn_mfma_f32_32x32x16_bf16(a, b, c, 0, 0, 0)

#define MMQ32(F) do { \
    __builtin_amdgcn_s_setprio(1); \
    acc[0][0] = MFMA32(F[0], F[4], acc[0][0]); \
    acc[0][1] = MFMA32(F[0], F[5], acc[0][1]); \
    acc[1][0] = MFMA32(F[1], F[4], acc[1][0]); \
    acc[1][1] = MFMA32(F[1], F[5], acc[1][1]); \
    acc[2][0] = MFMA32(F[2], F[4], acc[2][0]); \
    acc[2][1] = MFMA32(F[2], F[5], acc[2][1]); \
    acc[3][0] = MFMA32(F[3], F[4], acc[3][0]); \
    acc[3][1] = MFMA32(F[3], F[5], acc[3][1]); \
    __builtin_amdgcn_s_setprio(0); \
    SB0(); } while (0)

// One K-tile (4 phases). DSEL compile-time (0 / 65536).
#define TILE32(DSEL, T) do { \
    GATEV0(); BAR(); \
    RDP(f0, DSEL, 0); \
    RDP(f1, DSEL, 1); \
    STAGE(Ap, brow, (T) + 1, 0, 0); \
    STAGE(Bp, bcol, (T) + 1, 1, 0); \
    LGKM6(); MMQ32(f0); \
    RDP(f0, DSEL, 2); \
    STAGE(Ap, brow, (T) + 1, 0, 1); \
    STAGE(Bp, bcol, (T) + 1, 1, 1); \
    LGKM6(); MMQ32(f1); \
    RDP(f1, DSEL, 3); \
    LGKM6(); MMQ32(f0); \
    LGKM0(); MMQ32(f1); \
  } while (0)

__global__ __launch_bounds__(512, 2) void gemm_argmin_kernel(
    const __hip_bfloat16* __restrict__ Ap, const __hip_bfloat16* __restrict__ Bp,
    const float* __restrict__ xsq, const float* __restrict__ wsq,
    unsigned long long* __restrict__ keys)
{
  __shared__ char lds[131072];

  const int t = threadIdx.x;
  // XCD-aware: square 8x8 tile-chunk per XCD (r4-proven).
  const int id = blockIdx.x;
  const int xcd = id & 7;
  const int r_ = id >> 3;
  const int by = (xcd >> 2) * 8 + (r_ >> 3);
  const int bx = (xcd & 3) * 8 + (r_ & 7);
  const int brow = by * 256, bcol = bx * 256;

  const int lane = t & 63, wid = t >> 6;
  const int wm = wid >> 2, wn = wid & 3;   // wave tile 128 rows x 64 cols
  const int c31 = lane & 31;               // frag row/col
  const int kh = lane >> 5;                // k-half within 16-k granule
  const int swz = lane & 7;
  const int hi2 = (c31 >> 3) & 3;
  const unsigned fsw = (unsigned)(swz ^ hi2);   // f(row) for row = c31 mod 32

  // per-lane swizzled 16B-unit offsets for kk=0..3 (logical unit kk*2+kh)
  const unsigned ofk0 = (((0u + kh) ^ fsw) * 16);
  const unsigned ofk1 = (((2u + kh) ^ fsw) * 16);
  const unsigned ofk2 = (((4u + kh) ^ fsw) * 16);
  const unsigned ofk3 = (((6u + kh) ^ fsw) * 16);

  const unsigned lb = (unsigned)(uintptr_t)lds;
  const unsigned aB = lb + (unsigned)(wm * 16384 + c31 * 128);
  const unsigned bB = lb + (unsigned)(32768 + (wn >> 1) * 16384 +
                                      ((wn & 1) * 64 + c31) * 128);

  const int srow = lane >> 3;
  const int sunit0 = (lane & 7) ^ srow ^ ((2 * wid) & 3);
  const int sunit1 = (lane & 7) ^ srow ^ ((2 * wid + 1) & 3);

  f32x16 acc[4][2] = {};
  short8 f0[6], f1[6];

  // Prologue: stage tile0's 4 halves (drained at tile0 gate)
  STAGE(Ap, brow, 0, 0, 0);
  STAGE(Ap, brow, 0, 0, 1);
  STAGE(Bp, bcol, 0, 1, 0);
  STAGE(Bp, bcol, 0, 1, 1);

  for (int tt = 0; tt < NT; tt += 2) {
    TILE32(0, tt);
    TILE32(65536, tt + 1);
  }

  // Epilogue: s = (x_sq - 2*dot) + w_sq (reference fp32 rounding order).
  // 32x32 C/D (m74/m101, r2/r9-validated): col = lane&31,
  // row = (reg&3) + 8*(reg>>2) + 4*(lane>>5).
#pragma unroll
  for (int m = 0; m < 4; ++m) {
#pragma unroll
    for (int rg = 0; rg < 16; ++rg) {
      const int row = brow + wm * 128 + m * 32 + (rg & 3) + 8 * (rg >> 2) + 4 * kh;
      const float xs = xsq[row];
      unsigned long long best = ~0ULL;
#pragma unroll
      for (int n = 0; n < 2; ++n) {
        const int col = bcol + wn * 64 + n * 32 + c31;
        const float s = (xs - 2.0f * acc[m][n][rg]) + wsq[col];
        unsigned ub = __float_as_uint(s);
        ub = (ub & 0x80000000u) ? ~ub : (ub | 0x80000000u);
        const unsigned long long key =
            ((unsigned long long)ub << 32) | (unsigned)col;
        if (key < best) best = key;
      }
#pragma unroll
      for (int o = 1; o < 32; o <<= 1) {   // reduce within each 32-lane half
        const unsigned long long v = __shfl_xor(best, o);
        if (v < best) best = v;
      }
      if (c31 == 0) atomicMin(&keys[row], best);
    }
  }
}

// ---- transpose G [O,H] -> GT [H,O] ----
__global__ __launch_bounds__(256) void transposeG_kernel(
    const float* __restrict__ G, float* __restrict__ GT)
{
  __shared__ float tile[32][33];
  const int h0 = blockIdx.x * 32;
  const int o0 = blockIdx.y * 32;
  const int tx = threadIdx.x;
  const int ty = threadIdx.y;
#pragma unroll
  for (int j = 0; j < 4; ++j) {
    const int o = o0 + ty + j * 8;
    if (o < O_) tile[ty + j * 8][tx] = G[(size_t)o * H_ + h0 + tx];
  }
  __syncthreads();
  const int o = o0 + tx;
  if (o < O_) {
#pragma unroll
    for (int j = 0; j < 4; ++j)
      GT[(size_t)(h0 + ty + j * 8) * O_ + o] = tile[tx][ty + j * 8];
  }
}

// ---- winners + row gather ----
__global__ __launch_bounds__(256) void finalize_kernel(
    const unsigned long long* __restrict__ keys,
    const float* __restrict__ GT, float* __restrict__ out)
{
  const int b = blockIdx.x;
  const unsigned w = (unsigned)(keys[b] & 0xFFFFFFFFull);
  if (threadIdx.x == 0) out[(size_t)B_ * O_ + b] = (float)w;
  const float4* src = (const float4*)(GT + (size_t)w * O_);
  float4* dst = (float4*)(out + (size_t)b * O_);
  for (int i = threadIdx.x; i < O_ / 4; i += 256) dst[i] = src[i];
}

extern "C" void kernel_launch(void* const* d_in, const int* in_sizes, int n_in,
                              void* d_out, int out_size, void* d_ws, size_t ws_size,
                              hipStream_t stream)
{
  (void)in_sizes; (void)n_in; (void)out_size; (void)ws_size;
  const float* x = (const float*)d_in[0];
  const float* kw = (const float*)d_in[1];
  const float* gw = (const float*)d_in[2];
  float* out = (float*)d_out;

  char* ws = (char*)d_ws;
  // A' 16.78MB | B' 33.55MB | xsq 16KB | wsq 32KB | keys 32KB ; GT overlays A'/B'
  __hip_bfloat16* Ap = (__hip_bfloat16*)(ws);
  __hip_bfloat16* Bp = (__hip_bfloat16*)(ws + 16777216);
  float* xsq = (float*)(ws + 50331648);
  float* wsq = (float*)(ws + 50331648 + 16384);
  unsigned long long* keys = (unsigned long long*)(ws + 50331648 + 16384 + 32768);
  float* GT = (float*)(ws);  // dead A'/B' space after GEMM

  split_all_kernel<<<B_ + H_, 256, 0, stream>>>(x, kw, Ap, Bp, xsq, wsq, keys);
  gemm_argmin_kernel<<<512, 512, 0, stream>>>(Ap, Bp, xsq, wsq, keys);
  transposeG_kernel<<<dim3(H_ / 32, (O_ + 31) / 32), dim3(32, 8), 0, stream>>>(gw, GT);
  finalize_kernel<<<B_, 256, 0, stream>>>(keys, GT, out);
}